// Round 1
// baseline (948.342 us; speedup 1.0000x reference)
//
#include <hip/hip_runtime.h>

#define IN 128
#define PD 64
#define C1 64
#define C2 128
#define ICC 12
#define NOBJ 32

// ---------------------------------------------------------------------------
// K1: conv1 (12->64, 3x3 SAME) + ReLU + maxpool2x2  -> pooled (B,64,64,64) f32
// Thread = one pooled output pixel for one output channel.
// blockDim (64,4): x = pooled col, y covers 4 pooled rows. blockIdx:
//   x = pooled-row tile (16 tiles of 4), y = oc (uniform per block -> scalar
//   weight loads), z = batch.
// ---------------------------------------------------------------------------
__global__ __launch_bounds__(256) void k1_conv1_pool(
    const float* __restrict__ img, const float* __restrict__ w1,
    const float* __restrict__ b1, float* __restrict__ out)
{
  const int px = threadIdx.x;                   // 0..63
  const int py = blockIdx.x * 4 + threadIdx.y;  // 0..63
  const int oc = blockIdx.y;                    // 0..63
  const int b  = blockIdx.z;                    // 0..31

  const float* imgb = img + (size_t)b * ICC * IN * IN;
  const float* w    = w1 + oc * (ICC * 9);

  float s00 = 0.f, s01 = 0.f, s10 = 0.f, s11 = 0.f;
  const int y0 = 2 * py - 1, x0 = 2 * px - 1;

  for (int ic = 0; ic < ICC; ++ic) {
    const float* ip = imgb + ic * (IN * IN);
    float xin[4][4];
#pragma unroll
    for (int r = 0; r < 4; ++r) {
      const int yy = y0 + r;
#pragma unroll
      for (int c = 0; c < 4; ++c) {
        const int xx = x0 + c;
        float v = 0.f;
        if (yy >= 0 && yy < IN && xx >= 0 && xx < IN)
          v = ip[yy * IN + xx] * (1.f / 255.f);   // fold images/255 here
        xin[r][c] = v;
      }
    }
    const float* wp = w + ic * 9;
#pragma unroll
    for (int kr = 0; kr < 3; ++kr) {
#pragma unroll
      for (int kc = 0; kc < 3; ++kc) {
        const float wv = wp[kr * 3 + kc];
        s00 = fmaf(wv, xin[kr    ][kc    ], s00);
        s01 = fmaf(wv, xin[kr    ][kc + 1], s01);
        s10 = fmaf(wv, xin[kr + 1][kc    ], s10);
        s11 = fmaf(wv, xin[kr + 1][kc + 1], s11);
      }
    }
  }
  // bias is common across the 2x2 window; relu(max) == max(relu)
  float m = fmaxf(fmaxf(s00, s01), fmaxf(s10, s11)) + b1[oc];
  m = fmaxf(m, 0.f);
  out[(((size_t)b * C1 + oc) * PD + py) * PD + px] = m;
}

// ---------------------------------------------------------------------------
// K2: conv2 (64->128, 3x3 SAME) + bias + ReLU + per-roi-id segment max.
// Thread = 4 output rows x 8 output channels (32 f32 accumulators).
// blockDim (64,4): x = col, y = row-quad. blockIdx: x = 16-row tile (4),
//   y = oc-block of 8 (16, uniform -> scalar weight loads), z = batch.
// Epilogue: LDS atomicMax over [32 ids][8 oc] (float>=0 -> int-order trick),
// then one global atomicMax per slot. d_out must be pre-zeroed (matches
// segment_max empty-segment -> max(.,0) == 0 semantics).
// ---------------------------------------------------------------------------
__global__ __launch_bounds__(256) void k2_conv2_seg(
    const float* __restrict__ xin, const float* __restrict__ w2,
    const float* __restrict__ b2, const int* __restrict__ rois,
    float* __restrict__ out)
{
  const int x     = threadIdx.x;      // 0..63
  const int yq    = threadIdx.y;      // 0..3
  const int ytile = blockIdx.x;       // 0..3
  const int ocb   = blockIdx.y * 8;   // 0,8,...,120
  const int b     = blockIdx.z;       // 0..31
  const int ybase = ytile * 16 + yq * 4;

  const float* xb = xin + (size_t)b * C1 * PD * PD;

  float acc[8][4];
#pragma unroll
  for (int j = 0; j < 8; ++j)
#pragma unroll
    for (int r = 0; r < 4; ++r) acc[j][r] = 0.f;

  for (int ic = 0; ic < C1; ++ic) {
    const float* ip = xb + ic * (PD * PD);
    float v[6][3];
#pragma unroll
    for (int r = 0; r < 6; ++r) {
      const int yy = ybase - 1 + r;
#pragma unroll
      for (int c = 0; c < 3; ++c) {
        const int xx = x - 1 + c;
        float t = 0.f;
        if (yy >= 0 && yy < PD && xx >= 0 && xx < PD)
          t = ip[yy * PD + xx];
        v[r][c] = t;
      }
    }
    const float* wp = w2 + ((size_t)ocb * C1 + ic) * 9;  // w2[oc][ic][3][3]
#pragma unroll
    for (int j = 0; j < 8; ++j) {
      const float* wj = wp + j * (C1 * 9);
#pragma unroll
      for (int kr = 0; kr < 3; ++kr) {
#pragma unroll
        for (int kc = 0; kc < 3; ++kc) {
          const float wv = wj[kr * 3 + kc];
#pragma unroll
          for (int r = 0; r < 4; ++r)
            acc[j][r] = fmaf(wv, v[r + kr][kc], acc[j][r]);
        }
      }
    }
  }

  __shared__ int smax[NOBJ][8];
  const int t = threadIdx.y * 64 + threadIdx.x;  // 0..255 == 32*8 slots
  smax[t >> 3][t & 7] = 0;
  __syncthreads();

  const int* rb = rois + (size_t)b * IN * IN;
#pragma unroll
  for (int r = 0; r < 4; ++r) {
    const int y  = ybase + r;
    const int id = rb[(2 * y) * IN + 2 * x];   // ids = rois[:, ::2, ::2]
#pragma unroll
    for (int j = 0; j < 8; ++j) {
      float val = fmaxf(acc[j][r] + b2[ocb + j], 0.f);
      atomicMax(&smax[id][j], __float_as_int(val));
    }
  }
  __syncthreads();

  {
    const int id = t >> 3, j = t & 7;
    int* op = (int*)&out[((size_t)b * NOBJ + id) * C2 + ocb + j];
    atomicMax(op, smax[id][j]);
  }
}

extern "C" void kernel_launch(void* const* d_in, const int* in_sizes, int n_in,
                              void* d_out, int out_size, void* d_ws, size_t ws_size,
                              hipStream_t stream)
{
  (void)in_sizes; (void)n_in; (void)ws_size;
  const float* images = (const float*)d_in[0];
  const int*   rois   = (const int*)d_in[1];
  const float* w1     = (const float*)d_in[2];
  const float* b1     = (const float*)d_in[3];
  const float* w2     = (const float*)d_in[4];
  const float* b2     = (const float*)d_in[5];

  float* pooled = (float*)d_ws;          // 32*64*64*64 f32 = 33.5 MB
  float* outf   = (float*)d_out;         // (32, 32, 128) f32

  // segment-max identity: output = max(pooled, 0), absent id -> 0
  hipMemsetAsync(d_out, 0, (size_t)out_size * sizeof(float), stream);

  dim3 blk(64, 4, 1);
  dim3 g1(16, C1, 32);
  hipLaunchKernelGGL(k1_conv1_pool, g1, blk, 0, stream, images, w1, b1, pooled);

  dim3 g2(4, C2 / 8, 32);
  hipLaunchKernelGGL(k2_conv2_seg, g2, blk, 0, stream, pooled, w2, b2, rois, outf);
}

// Round 2
// 316.513 us; speedup vs baseline: 2.9962x; 2.9962x over previous
//
#include <hip/hip_runtime.h>

#define IN 128
#define PD 64
#define C1 64
#define C2 128
#define ICC 12
#define NOBJ 32

// ---------------------------------------------------------------------------
// K1: conv1 (12->64, 3x3 SAME) + ReLU + maxpool2x2 -> pooled (B,64,64,64) f32
// Block = 64x4 pooled pixels, 16 output channels per thread.
// Per ic: stage 10x128 input rows (+zero halo) into LDS [10][132] with
// coalesced float4 loads, then each thread reads its 4x4 window (stride-2
// lanes -> 2-way LDS conflict = free) and runs 16 oc x 36 FMA.
// /255 scaling folded into epilogue (linear, commutes with maxpool).
// ---------------------------------------------------------------------------
__global__ __launch_bounds__(256) void k1_conv1_pool(
    const float* __restrict__ img, const float* __restrict__ w1,
    const float* __restrict__ b1, float* __restrict__ out)
{
  const int px  = threadIdx.x;            // 0..63 pooled col
  const int qy  = threadIdx.y;            // 0..3
  const int P   = blockIdx.x * 4;         // pooled row base
  const int ocb = blockIdx.y * 16;        // 0,16,32,48
  const int b   = blockIdx.z;             // 0..31
  const int t   = qy * 64 + px;           // 0..255

  __shared__ float tile[10][132];

  // zero the 4 pad columns of each of the 10 rows (once; stages never touch them)
  if (t < 40) {
    const int r = t >> 2, k = t & 3;
    tile[r][(k < 2) ? k : (k + 128)] = 0.f;   // cols 0,1,130,131
  }

  const float* imgb = img + (size_t)b * ICC * IN * IN;
  const int irow0 = 2 * P - 1;

  float acc[16][4];
#pragma unroll
  for (int j = 0; j < 16; ++j)
#pragma unroll
    for (int p = 0; p < 4; ++p) acc[j][p] = 0.f;

  for (int ic = 0; ic < ICC; ++ic) {
    const float* ip = imgb + ic * (IN * IN);
    __syncthreads();  // previous iteration's reads done before overwrite
    // stage: 10 rows x 32 float4 = 320 slots over 256 threads
#pragma unroll
    for (int s = t; s < 320; s += 256) {
      const int r  = s >> 5;               // 0..9
      const int c4 = (s & 31) << 2;        // 0,4,...,124
      const int gy = irow0 + r;
      float4 v = make_float4(0.f, 0.f, 0.f, 0.f);
      if (gy >= 0 && gy < IN)
        v = *reinterpret_cast<const float4*>(ip + gy * IN + c4);
      tile[r][c4 + 2] = v.x;
      tile[r][c4 + 3] = v.y;
      tile[r][c4 + 4] = v.z;
      tile[r][c4 + 5] = v.w;
    }
    __syncthreads();

    float xw[4][4];
#pragma unroll
    for (int r = 0; r < 4; ++r)
#pragma unroll
      for (int c = 0; c < 4; ++c)
        xw[r][c] = tile[2 * qy + r][2 * px + 1 + c];

#pragma unroll
    for (int j = 0; j < 16; ++j) {
      const float* wp = w1 + (size_t)(ocb + j) * (ICC * 9) + ic * 9;  // uniform -> s_load
#pragma unroll
      for (int kr = 0; kr < 3; ++kr) {
#pragma unroll
        for (int kc = 0; kc < 3; ++kc) {
          const float wv = wp[kr * 3 + kc];
          acc[j][0] = fmaf(wv, xw[kr    ][kc    ], acc[j][0]);
          acc[j][1] = fmaf(wv, xw[kr    ][kc + 1], acc[j][1]);
          acc[j][2] = fmaf(wv, xw[kr + 1][kc    ], acc[j][2]);
          acc[j][3] = fmaf(wv, xw[kr + 1][kc + 1], acc[j][3]);
        }
      }
    }
  }

  const int py = P + qy;
#pragma unroll
  for (int j = 0; j < 16; ++j) {
    float m = fmaxf(fmaxf(acc[j][0], acc[j][1]), fmaxf(acc[j][2], acc[j][3]));
    m = fmaxf(fmaf(m, 1.f / 255.f, b1[ocb + j]), 0.f);  // /255 folded; relu
    out[(((size_t)b * C1 + (ocb + j)) * PD + py) * PD + px] = m;
  }
}

// ---------------------------------------------------------------------------
// K2: conv2 (64->128, 3x3 SAME) + bias + ReLU + per-roi-id segment max.
// Thread = 4 output rows x 8 output channels (32 f32 accumulators).
// ---------------------------------------------------------------------------
__global__ __launch_bounds__(256) void k2_conv2_seg(
    const float* __restrict__ xin, const float* __restrict__ w2,
    const float* __restrict__ b2, const int* __restrict__ rois,
    float* __restrict__ out)
{
  const int x     = threadIdx.x;      // 0..63
  const int yq    = threadIdx.y;      // 0..3
  const int ytile = blockIdx.x;       // 0..3
  const int ocb   = blockIdx.y * 8;   // 0,8,...,120
  const int b     = blockIdx.z;       // 0..31
  const int ybase = ytile * 16 + yq * 4;

  const float* xb = xin + (size_t)b * C1 * PD * PD;

  float acc[8][4];
#pragma unroll
  for (int j = 0; j < 8; ++j)
#pragma unroll
    for (int r = 0; r < 4; ++r) acc[j][r] = 0.f;

  for (int ic = 0; ic < C1; ++ic) {
    const float* ip = xb + ic * (PD * PD);
    float v[6][3];
#pragma unroll
    for (int r = 0; r < 6; ++r) {
      const int yy = ybase - 1 + r;
#pragma unroll
      for (int c = 0; c < 3; ++c) {
        const int xx = x - 1 + c;
        float t = 0.f;
        if (yy >= 0 && yy < PD && xx >= 0 && xx < PD)
          t = ip[yy * PD + xx];
        v[r][c] = t;
      }
    }
    const float* wp = w2 + ((size_t)ocb * C1 + ic) * 9;  // w2[oc][ic][3][3]
#pragma unroll
    for (int j = 0; j < 8; ++j) {
      const float* wj = wp + j * (C1 * 9);
#pragma unroll
      for (int kr = 0; kr < 3; ++kr) {
#pragma unroll
        for (int kc = 0; kc < 3; ++kc) {
          const float wv = wj[kr * 3 + kc];
#pragma unroll
          for (int r = 0; r < 4; ++r)
            acc[j][r] = fmaf(wv, v[r + kr][kc], acc[j][r]);
        }
      }
    }
  }

  __shared__ int smax[NOBJ][8];
  const int t = threadIdx.y * 64 + threadIdx.x;  // 0..255 == 32*8 slots
  smax[t >> 3][t & 7] = 0;
  __syncthreads();

  const int* rb = rois + (size_t)b * IN * IN;
#pragma unroll
  for (int r = 0; r < 4; ++r) {
    const int y  = ybase + r;
    const int id = rb[(2 * y) * IN + 2 * x];   // ids = rois[:, ::2, ::2]
#pragma unroll
    for (int j = 0; j < 8; ++j) {
      float val = fmaxf(acc[j][r] + b2[ocb + j], 0.f);
      atomicMax(&smax[id][j], __float_as_int(val));
    }
  }
  __syncthreads();

  {
    const int id = t >> 3, j = t & 7;
    int* op = (int*)&out[((size_t)b * NOBJ + id) * C2 + ocb + j];
    atomicMax(op, smax[id][j]);
  }
}

extern "C" void kernel_launch(void* const* d_in, const int* in_sizes, int n_in,
                              void* d_out, int out_size, void* d_ws, size_t ws_size,
                              hipStream_t stream)
{
  (void)in_sizes; (void)n_in; (void)ws_size;
  const float* images = (const float*)d_in[0];
  const int*   rois   = (const int*)d_in[1];
  const float* w1     = (const float*)d_in[2];
  const float* b1     = (const float*)d_in[3];
  const float* w2     = (const float*)d_in[4];
  const float* b2     = (const float*)d_in[5];

  float* pooled = (float*)d_ws;          // 32*64*64*64 f32 = 33.5 MB
  float* outf   = (float*)d_out;         // (32, 32, 128) f32

  // segment-max identity: output = max(pooled, 0), absent id -> 0
  hipMemsetAsync(d_out, 0, (size_t)out_size * sizeof(float), stream);

  dim3 blk(64, 4, 1);
  dim3 g1(16, C1 / 16, 32);
  hipLaunchKernelGGL(k1_conv1_pool, g1, blk, 0, stream, images, w1, b1, pooled);

  dim3 g2(4, C2 / 8, 32);
  hipLaunchKernelGGL(k2_conv2_seg, g2, blk, 0, stream, pooled, w2, b2, rois, outf);
}

// Round 3
// 178.583 us; speedup vs baseline: 5.3104x; 1.7724x over previous
//
#include <hip/hip_runtime.h>

#define IN 128
#define PD 64
#define C1 64
#define C2 128
#define ICC 12
#define NOBJ 32
#define PADW 66   // 64 + 1 halo each side

typedef __attribute__((ext_vector_type(8))) short bf16x8;
typedef __attribute__((ext_vector_type(4))) float f32x4;

static __device__ __forceinline__ unsigned short f2bf(float f) {
  unsigned u = __float_as_uint(f);
  return (unsigned short)((u + 0x7FFFu + ((u >> 16) & 1u)) >> 16);  // RNE
}

// ---------------------------------------------------------------------------
// K0: pack w2 (128,64,3,3) f32 -> wp[tap][oc][ic] bf16  (147 KB)
// ---------------------------------------------------------------------------
__global__ __launch_bounds__(256) void k0_pack_w(
    const float* __restrict__ w2, unsigned short* __restrict__ wp)
{
  int i = blockIdx.x * 256 + threadIdx.x;
  if (i < 9 * C2 * C1) {
    int tap = i / (C2 * C1);
    int rem = i - tap * (C2 * C1);
    int oc = rem >> 6, ic = rem & 63;
    wp[i] = f2bf(w2[(oc * C1 + ic) * 9 + tap]);
  }
}

// ---------------------------------------------------------------------------
// K1: conv1 (12->64) + ReLU + maxpool2x2, f32 math, LDS-staged input.
// Output: padded NHWC bf16 xpad[B][66][66][64] (border pre-zeroed by memset).
// ---------------------------------------------------------------------------
__global__ __launch_bounds__(256) void k1_conv1_pool(
    const float* __restrict__ img, const float* __restrict__ w1,
    const float* __restrict__ b1, unsigned short* __restrict__ xpad)
{
  const int px  = threadIdx.x;            // 0..63 pooled col
  const int qy  = threadIdx.y;            // 0..3
  const int P   = blockIdx.x * 4;         // pooled row base
  const int ocb = blockIdx.y * 16;        // 0,16,32,48
  const int b   = blockIdx.z;             // 0..31
  const int t   = qy * 64 + px;           // 0..255

  __shared__ float tile[10][132];

  if (t < 40) {
    const int r = t >> 2, k = t & 3;
    tile[r][(k < 2) ? k : (k + 128)] = 0.f;   // pad cols 0,1,130,131
  }

  const float* imgb = img + (size_t)b * ICC * IN * IN;
  const int irow0 = 2 * P - 1;

  float acc[16][4];
#pragma unroll
  for (int j = 0; j < 16; ++j)
#pragma unroll
    for (int p = 0; p < 4; ++p) acc[j][p] = 0.f;

  for (int ic = 0; ic < ICC; ++ic) {
    const float* ip = imgb + ic * (IN * IN);
    __syncthreads();
#pragma unroll
    for (int s = t; s < 320; s += 256) {
      const int r  = s >> 5;
      const int c4 = (s & 31) << 2;
      const int gy = irow0 + r;
      float4 v = make_float4(0.f, 0.f, 0.f, 0.f);
      if (gy >= 0 && gy < IN)
        v = *reinterpret_cast<const float4*>(ip + gy * IN + c4);
      tile[r][c4 + 2] = v.x;
      tile[r][c4 + 3] = v.y;
      tile[r][c4 + 4] = v.z;
      tile[r][c4 + 5] = v.w;
    }
    __syncthreads();

    float xw[4][4];
#pragma unroll
    for (int r = 0; r < 4; ++r)
#pragma unroll
      for (int c = 0; c < 4; ++c)
        xw[r][c] = tile[2 * qy + r][2 * px + 1 + c];

#pragma unroll
    for (int j = 0; j < 16; ++j) {
      const float* wp = w1 + (size_t)(ocb + j) * (ICC * 9) + ic * 9;
#pragma unroll
      for (int kr = 0; kr < 3; ++kr) {
#pragma unroll
        for (int kc = 0; kc < 3; ++kc) {
          const float wv = wp[kr * 3 + kc];
          acc[j][0] = fmaf(wv, xw[kr    ][kc    ], acc[j][0]);
          acc[j][1] = fmaf(wv, xw[kr    ][kc + 1], acc[j][1]);
          acc[j][2] = fmaf(wv, xw[kr + 1][kc    ], acc[j][2]);
          acc[j][3] = fmaf(wv, xw[kr + 1][kc + 1], acc[j][3]);
        }
      }
    }
  }

  const int py = P + qy;
  unsigned int pk[8];
#pragma unroll
  for (int j = 0; j < 16; ++j) {
    float m = fmaxf(fmaxf(acc[j][0], acc[j][1]), fmaxf(acc[j][2], acc[j][3]));
    m = fmaxf(fmaf(m, 1.f / 255.f, b1[ocb + j]), 0.f);
    unsigned short h = f2bf(m);
    if (j & 1) pk[j >> 1] |= ((unsigned int)h) << 16;
    else       pk[j >> 1]  = h;
  }
  // xpad[b][py+1][px+1][ocb..ocb+15]
  unsigned short* dst = xpad + ((((size_t)b * PADW + (py + 1)) * PADW) + (px + 1)) * C1 + ocb;
  reinterpret_cast<uint4*>(dst)[0] = make_uint4(pk[0], pk[1], pk[2], pk[3]);
  reinterpret_cast<uint4*>(dst)[1] = make_uint4(pk[4], pk[5], pk[6], pk[7]);
}

// ---------------------------------------------------------------------------
// K2: conv2 as implicit GEMM via MFMA bf16 + bias/ReLU + segment-max.
// Block: 8x8 spatial x 128 oc; 4 waves = 2M x 2N; wave tile 32m x 64oc.
// X tile (10x10x64 bf16) staged once in LDS, XOR-swizzled (c ^= s&7 per 16B
// slot) so fragment ds_read_b128 is <=2-way bank conflict.
// K-loop: 9 taps x 2 k-chunks of 32 ic; mfma_f32_16x16x32_bf16.
// ---------------------------------------------------------------------------
__global__ __launch_bounds__(256) void k2_mfma(
    const unsigned short* __restrict__ xpad, const unsigned short* __restrict__ wp,
    const float* __restrict__ b2, const int* __restrict__ rois,
    float* __restrict__ out)
{
  const int t  = threadIdx.x;
  const int l  = t & 63, w = t >> 6;
  const int wm = w >> 1, wn = w & 1;
  const int bx = blockIdx.x & 7, by = blockIdx.x >> 3;
  const int b  = blockIdx.y;
  const int l15 = l & 15, l16 = l >> 4;

  __shared__ uint4 xs4[800];            // 100 rows x 8 slots x 16B = 12.8 KB
  __shared__ int   smax[NOBJ * C2];     // 16 KB
  __shared__ int   ids_s[64];

  // ---- stage X tile ----
  const unsigned short* xb = xpad + (size_t)b * PADW * PADW * C1;
  for (int s16 = t; s16 < 800; s16 += 256) {
    int r = s16 >> 3, c = s16 & 7;          // r = y*10+x in [0,100)
    int y = (r * 205) >> 11;                // r/10
    int x = r - y * 10;
    int gy = by * 8 + y, gx = bx * 8 + x;
    const uint4* src = reinterpret_cast<const uint4*>(xb + ((size_t)gy * PADW + gx) * C1) + c;
    xs4[r * 8 + (c ^ (r & 7))] = *src;
  }
  // ---- ids + smax init ----
  if (t < 64) {
    int py = t >> 3, px = t & 7;
    ids_s[t] = rois[((size_t)b * IN + 2 * (by * 8 + py)) * IN + 2 * (bx * 8 + px)];
  }
#pragma unroll
  for (int s = t; s < NOBJ * C2; s += 256) smax[s] = 0;
  __syncthreads();

  f32x4 acc[2][4];
#pragma unroll
  for (int mf = 0; mf < 2; ++mf)
#pragma unroll
    for (int nf = 0; nf < 4; ++nf) acc[mf][nf] = (f32x4){0.f, 0.f, 0.f, 0.f};

  const char* xs_raw = reinterpret_cast<const char*>(xs4);

#pragma unroll
  for (int kr = 0; kr < 3; ++kr) {
#pragma unroll
    for (int kc = 0; kc < 3; ++kc) {
      const int tap = kr * 3 + kc;
#pragma unroll
      for (int k2 = 0; k2 < 2; ++k2) {
        bf16x8 a[2], bw[4];
#pragma unroll
        for (int mf = 0; mf < 2; ++mf) {
          int m_loc = wm * 32 + mf * 16 + l15;
          int py = m_loc >> 3, px = m_loc & 7;
          int s = (py + kr) * 10 + (px + kc);
          int c = (k2 * 4 + l16) ^ (s & 7);
          a[mf] = *reinterpret_cast<const bf16x8*>(xs_raw + s * 128 + c * 16);
        }
#pragma unroll
        for (int nf = 0; nf < 4; ++nf) {
          int oc = wn * 64 + nf * 16 + l15;
          bw[nf] = *reinterpret_cast<const bf16x8*>(
              wp + ((size_t)tap * C2 + oc) * C1 + k2 * 32 + l16 * 8);
        }
#pragma unroll
        for (int mf = 0; mf < 2; ++mf)
#pragma unroll
          for (int nf = 0; nf < 4; ++nf)
            acc[mf][nf] = __builtin_amdgcn_mfma_f32_16x16x32_bf16(
                a[mf], bw[nf], acc[mf][nf], 0, 0, 0);
      }
    }
  }

  // ---- epilogue: bias + relu + segment max ----
  float bias[4];
#pragma unroll
  for (int nf = 0; nf < 4; ++nf) bias[nf] = b2[wn * 64 + nf * 16 + l15];

#pragma unroll
  for (int mf = 0; mf < 2; ++mf) {
#pragma unroll
    for (int reg = 0; reg < 4; ++reg) {
      int m_loc = wm * 32 + mf * 16 + l16 * 4 + reg;   // C/D row (m89 mapping)
      int id = ids_s[m_loc];
#pragma unroll
      for (int nf = 0; nf < 4; ++nf) {
        int oc = wn * 64 + nf * 16 + l15;              // C/D col
        float val = fmaxf(acc[mf][nf][reg] + bias[nf], 0.f);
        atomicMax(&smax[id * C2 + oc], __float_as_int(val));
      }
    }
  }
  __syncthreads();

  int* ob = reinterpret_cast<int*>(out) + (size_t)b * NOBJ * C2;
#pragma unroll
  for (int s = t; s < NOBJ * C2; s += 256) {
    int v = smax[s];
    if (v > 0) atomicMax(&ob[s], v);
  }
}

extern "C" void kernel_launch(void* const* d_in, const int* in_sizes, int n_in,
                              void* d_out, int out_size, void* d_ws, size_t ws_size,
                              hipStream_t stream)
{
  (void)in_sizes; (void)n_in; (void)ws_size;
  const float* images = (const float*)d_in[0];
  const int*   rois   = (const int*)d_in[1];
  const float* w1     = (const float*)d_in[2];
  const float* b1     = (const float*)d_in[3];
  const float* w2     = (const float*)d_in[4];
  const float* b2     = (const float*)d_in[5];

  const size_t xpad_bytes = (size_t)32 * PADW * PADW * C1 * 2;   // 17,842,176 B
  unsigned short* xpad = (unsigned short*)d_ws;
  unsigned short* wpk  = (unsigned short*)((char*)d_ws + xpad_bytes);  // 147,456 B

  // zero border of xpad (interior overwritten by k1) + zero output (segment-max
  // identity: absent id -> 0, and final max(.,0))
  hipMemsetAsync(d_ws, 0, xpad_bytes, stream);
  hipMemsetAsync(d_out, 0, (size_t)out_size * sizeof(float), stream);

  hipLaunchKernelGGL(k0_pack_w, dim3(288), dim3(256), 0, stream, w2, wpk);

  dim3 blk1(64, 4, 1);
  dim3 g1(16, C1 / 16, 32);
  hipLaunchKernelGGL(k1_conv1_pool, g1, blk1, 0, stream, images, w1, b1, xpad);

  dim3 g2(64, 32, 1);
  hipLaunchKernelGGL(k2_mfma, g2, dim3(256), 0, stream, xpad, wpk, b2, rois,
                     (float*)d_out);
}